// Round 9
// baseline (105.215 us; speedup 1.0000x reference)
//
#include <hip/hip_runtime.h>

#define N_NODES 100000
#define N_EDGES 1000000
#define HIDDEN 64

// ---- range-pass geometry ----
#define N_RANGES 8
#define C_RANGE 12544                    // 8*12544 = 100352 >= 100000; bins 50,176 B
#define N_SLICES 64                      // grid = 8*64 = 512 blocks = exactly 2/CU
#define ES (N_EDGES / N_SLICES)          // 15625 edges per slice (exact, no global tail)
#define A_THREADS 512
#define WAVES (A_THREADS / 64)
#define BUFCAP 128                       // per-wave queue: cnt<=63 + <=64 new = <=127
#define A_GRID (N_RANGES * N_SLICES)

// kc[0..3]=(W1@Wout)[k], kc[4]=b1.Wout, kc[5..8]=W1[k][0], kc[9..12]=W1[k][1],
// kc[13]=b1[0], kc[14]=b1[1], kc[15]=Wout[0], kc[16]=Wout[1], kc[17]=bout[0]
__device__ __forceinline__ void compute_consts(
    const float* __restrict__ W1, const float* __restrict__ b1,
    const float* __restrict__ Wout, const float* __restrict__ bout,
    float* kc, int tid) {
    if (tid < 64) {
        float wj = Wout[tid];
        float p0 = W1[0 * HIDDEN + tid] * wj;
        float p1 = W1[1 * HIDDEN + tid] * wj;
        float p2 = W1[2 * HIDDEN + tid] * wj;
        float p3 = W1[3 * HIDDEN + tid] * wj;
        float pb = b1[tid] * wj;
        #pragma unroll
        for (int off = 32; off > 0; off >>= 1) {
            p0 += __shfl_down(p0, off);
            p1 += __shfl_down(p1, off);
            p2 += __shfl_down(p2, off);
            p3 += __shfl_down(p3, off);
            pb += __shfl_down(pb, off);
        }
        if (tid < 4) {
            kc[5 + tid] = W1[tid * HIDDEN + 0];
            kc[9 + tid] = W1[tid * HIDDEN + 1];
        }
        if (tid == 0) {
            kc[0] = p0; kc[1] = p1; kc[2] = p2; kc[3] = p3; kc[4] = pb;
            kc[13] = b1[0]; kc[14] = b1[1];
            kc[15] = Wout[0]; kc[16] = Wout[1];
            kc[17] = bout[0];
        }
    }
}

__device__ __forceinline__ float contrib(
    float4 xe, float cs, float sn_signed,
    float c0, float c1, float c2, float c3, float cb,
    float a0, float a1, float a2, float a3,
    float g0, float g1, float g2, float g3,
    float b10, float b11, float w0, float w1) {
    float h0 = xe.x * a0 + xe.y * a1 + xe.z * a2 + xe.w * a3 + b10;
    float h1 = xe.x * g0 + xe.y * g1 + xe.z * g2 + xe.w * g3 + b11;
    float d  = xe.x * c0 + xe.y * c1 + xe.z * c2 + xe.w * c3 + cb;
    float a  = h0 * w0 + h1 * w1;
    float b  = h0 * w1 - h1 * w0;
    return cs * a + sn_signed * b + (d - a);
}

// ---- Kernel A: wave-level ballot compaction. Scan is cheap & coalesced;
// gathers happen only in dense 64-wide drains (2M total, fully active lanes).
// No __syncthreads in the main loop; no shared counters (ballot+popc only).
__global__ __launch_bounds__(A_THREADS) void range_kernel(
    const int2* __restrict__ edges, const float* __restrict__ phases,
    const float4* __restrict__ x4,
    const float* __restrict__ W1, const float* __restrict__ b1,
    const float* __restrict__ Wout, const float* __restrict__ bout,
    float* __restrict__ part) {
    __shared__ float bins[C_RANGE];               // 50,176 B
    __shared__ uint2 wbuf[WAVES][BUFCAP];         // 8,192 B
    __shared__ float kc[18];
    const int tid  = threadIdx.x;
    const int lane = tid & 63;
    const int w    = tid >> 6;
    const int r    = blockIdx.x >> 6;             // range index
    const int s    = blockIdx.x & 63;             // edge-slice index

    compute_consts(W1, b1, Wout, bout, kc, tid);
    {
        float4 z = make_float4(0.f, 0.f, 0.f, 0.f);
        float4* b4 = (float4*)bins;
        for (int j = tid; j < C_RANGE / 4; j += A_THREADS) b4[j] = z;
    }
    __syncthreads();

    const float c0 = kc[0], c1 = kc[1], c2 = kc[2], c3 = kc[3], cb = kc[4];
    const float a0 = kc[5], a1 = kc[6], a2 = kc[7], a3 = kc[8];
    const float g0 = kc[9], g1 = kc[10], g2 = kc[11], g3 = kc[12];
    const float b10 = kc[13], b11 = kc[14], w0 = kc[15], w1 = kc[16];

    const int nlo = r * C_RANGE;
    const int e0 = s * ES, e1 = e0 + ES;
    uint2* __restrict__ buf = wbuf[w];
    int cnt = 0;                                   // wave-uniform by construction
    const unsigned long long lml = (1ull << lane) - 1ull;

    auto process = [&](uint2 it) {
        unsigned pk = it.x;
        int dest = pk & 0x3FFFu;
        float sg = (pk & 0x4000u) ? -1.0f : 1.0f;
        int src = pk >> 15;
        float sn, cs;
        __sincosf(__uint_as_float(it.y), &sn, &cs);
        float4 xs = x4[src];
        float val = contrib(xs, cs, sg * sn, c0, c1, c2, c3, cb,
                            a0, a1, a2, a3, g0, g1, g2, g3, b10, b11, w0, w1);
        atomicAdd(&bins[dest], val);
    };

    for (int base = e0 + w * 64; base < e1; base += A_THREADS) {
        int e = base + lane;
        bool inb = e < e1;
        int eload = inb ? e : (N_EDGES - 1);       // clamp OOB lane loads
        int2 ed = edges[eload];
        float ph = phases[eload];
        unsigned jv = (unsigned)(ed.y - nlo);      // dest v, src u, +sn
        unsigned ju = (unsigned)(ed.x - nlo);      // dest u, src v, -sn
        bool pv = inb && (jv < C_RANGE);
        bool pu = inb && (ju < C_RANGE);

        unsigned long long mv = __ballot(pv);
        if (pv) buf[cnt + __popcll(mv & lml)] =
            make_uint2(jv | ((unsigned)ed.x << 15), __float_as_uint(ph));
        cnt += __popcll(mv);
        if (cnt >= 64) {                           // wave-uniform drain
            cnt -= 64;
            asm volatile("s_waitcnt lgkmcnt(0)" ::: "memory");
            process(buf[cnt + lane]);
        }

        unsigned long long mu = __ballot(pu);
        if (pu) buf[cnt + __popcll(mu & lml)] =
            make_uint2(ju | 0x4000u | ((unsigned)ed.y << 15), __float_as_uint(ph));
        cnt += __popcll(mu);
        if (cnt >= 64) {
            cnt -= 64;
            asm volatile("s_waitcnt lgkmcnt(0)" ::: "memory");
            process(buf[cnt + lane]);
        }
    }
    // final partial drain
    asm volatile("s_waitcnt lgkmcnt(0)" ::: "memory");
    if (lane < cnt) process(buf[lane]);

    __syncthreads();
    float4* __restrict__ d4 = (float4*)(part + (size_t)blockIdx.x * C_RANGE);
    const float4* b4 = (const float4*)bins;
    for (int j = tid; j < C_RANGE / 4; j += A_THREADS) d4[j] = b4[j];
}

// ---- Kernel B: out[i] = sum_s part[(r,s)][j] + x_i.(W1@Wout) + b1.Wout + bout
__global__ __launch_bounds__(A_THREADS) void reduce_kernel(
    const float4* __restrict__ x4,
    const float* __restrict__ W1, const float* __restrict__ b1,
    const float* __restrict__ Wout, const float* __restrict__ bout,
    const float* __restrict__ part, float* __restrict__ out) {
    __shared__ float kc[18];
    compute_consts(W1, b1, Wout, bout, kc, threadIdx.x);
    __syncthreads();
    int i = blockIdx.x * A_THREADS + threadIdx.x;
    if (i >= N_NODES) return;
    int r = i / C_RANGE;
    int j = i - r * C_RANGE;
    const float* __restrict__ p = part + ((size_t)r * N_SLICES) * C_RANGE + j;
    float sum = 0.0f;
    #pragma unroll 16
    for (int s = 0; s < N_SLICES; s++) sum += p[(size_t)s * C_RANGE];
    float4 xi = x4[i];
    out[i] = sum + xi.x * kc[0] + xi.y * kc[1] + xi.z * kc[2] + xi.w * kc[3]
           + kc[4] + kc[17];
}

// ---- Fallback (ws too small): direct device atomics ----------------------
__global__ void precompute_kernel(const float* __restrict__ W1,
                                  const float* __restrict__ b1,
                                  const float* __restrict__ Wout,
                                  const float* __restrict__ bout,
                                  float* __restrict__ consts) {
    __shared__ float kc[18];
    compute_consts(W1, b1, Wout, bout, kc, threadIdx.x);
    __syncthreads();
    if (threadIdx.x < 18) consts[threadIdx.x] = kc[threadIdx.x];
}

__global__ void edge_atomic_kernel(const int2* __restrict__ edges,
                                   const float* __restrict__ phases,
                                   const float4* __restrict__ x4,
                                   const float* __restrict__ consts,
                                   float* __restrict__ rep) {
    int e = blockIdx.x * blockDim.x + threadIdx.x;
    if (e >= N_EDGES) return;
    float c0 = consts[0], c1 = consts[1], c2 = consts[2], c3 = consts[3];
    float cb = consts[4];
    float a0 = consts[5], a1 = consts[6], a2 = consts[7], a3 = consts[8];
    float g0 = consts[9], g1 = consts[10], g2 = consts[11], g3 = consts[12];
    float b10 = consts[13], b11 = consts[14], w0 = consts[15], w1 = consts[16];
    int2 ed = edges[e];
    float ph = phases[e];
    float sn, cs;
    __sincosf(ph, &sn, &cs);
    float4 xu = x4[ed.x];
    float4 xv = x4[ed.y];
    atomicAdd(rep + ed.y, contrib(xu, cs,  sn, c0,c1,c2,c3,cb, a0,a1,a2,a3, g0,g1,g2,g3, b10,b11,w0,w1));
    atomicAdd(rep + ed.x, contrib(xv, cs, -sn, c0,c1,c2,c3,cb, a0,a1,a2,a3, g0,g1,g2,g3, b10,b11,w0,w1));
}

__global__ void final_kernel(const float4* __restrict__ x4,
                             const float* __restrict__ consts,
                             const float* __restrict__ rep,
                             float* __restrict__ out) {
    int i = blockIdx.x * blockDim.x + threadIdx.x;
    if (i >= N_NODES) return;
    float4 xi = x4[i];
    out[i] = rep[i] + xi.x * consts[0] + xi.y * consts[1] + xi.z * consts[2]
           + xi.w * consts[3] + consts[4] + consts[17];
}

extern "C" void kernel_launch(void* const* d_in, const int* in_sizes, int n_in,
                              void* d_out, int out_size, void* d_ws, size_t ws_size,
                              hipStream_t stream) {
    const float* x      = (const float*)d_in[0];
    const int*   edges  = (const int*)d_in[1];
    const float* W1     = (const float*)d_in[2];
    const float* b1     = (const float*)d_in[3];
    const float* phases = (const float*)d_in[4];
    const float* Wout   = (const float*)d_in[5];
    const float* bout   = (const float*)d_in[6];
    float* out = (float*)d_out;

    const size_t part_bytes =
        (size_t)A_GRID * C_RANGE * sizeof(float);   // ~25.7 MB

    if (ws_size >= part_bytes) {
        float* part = (float*)d_ws;
        // No memset needed: every part slot is written by exactly one block.
        range_kernel<<<A_GRID, A_THREADS, 0, stream>>>(
            (const int2*)edges, phases, (const float4*)x,
            W1, b1, Wout, bout, part);
        reduce_kernel<<<(N_NODES + A_THREADS - 1) / A_THREADS, A_THREADS, 0, stream>>>(
            (const float4*)x, W1, b1, Wout, bout, part, out);
    } else {
        float* consts = (float*)d_ws;
        float* rep    = (float*)((char*)d_ws + 256);
        hipMemsetAsync(rep, 0, N_NODES * sizeof(float), stream);
        precompute_kernel<<<1, 64, 0, stream>>>(W1, b1, Wout, bout, consts);
        edge_atomic_kernel<<<(N_EDGES + 255) / 256, 256, 0, stream>>>(
            (const int2*)edges, phases, (const float4*)x, consts, rep);
        final_kernel<<<(N_NODES + 255) / 256, 256, 0, stream>>>(
            (const float4*)x, consts, rep, out);
    }
}